// Round 6
// baseline (263.676 us; speedup 1.0000x reference)
//
#include <hip/hip_runtime.h>

// RelativeSAMAttention: B=4,H=8,N=1024,DH=128. Outputs FP32: out[B,H,N,DH] ++ scores[B,H,N,N].
//
// R9: R8 + 2-tile (128-col) chunking in both loops + LDS-merged O epilogue.
//   - pass1: sK chunk [128m][128dh]=32KB dbuf (64KB), 8 barriers (was 16), stage latency
//     hidden under 2 tiles of QK^T+distmap.
//   - replay: sVt chunk [128dh][128m]=32KB dbuf (same region), sP single [32][128] 8KB,
//     2 barriers/chunk; stageV issued after barrier A -> drains at B under PV+stores
//     (stage-drain events 32 -> 16).
//   - O epilogue: oacc -> LDS fp32 [32][136] -> cooperative full-512B-line NT stores
//     (kills the +23MB partial-line RMW on out).
//   - s_red/s_inv alias the sP region; LDS 72KB -> 2 blocks/CU; launch_bounds(512,4)
//     (R6/R7b lesson: tighter caps spill the 32-VGPR score cache).

typedef __attribute__((ext_vector_type(8))) short short8;
typedef __attribute__((ext_vector_type(4))) float f32x4;

#define OUT_ELEMS 4194304ull
#define WS_K      0ull           //  8388608 B bf16 K [bh][m][dh]
#define WS_VT     8388608ull     //  8388608 B bf16 V^T [bh][dh][m]
#define WS_CS     16777216ull    //      128 B fp32 cs[32]

__device__ __forceinline__ unsigned short f2bf(float f) {
    unsigned u = __builtin_bit_cast(unsigned, f);
    u += 0x7FFFu + ((u >> 16) & 1u);
    return (unsigned short)(u >> 16);
}
__device__ __forceinline__ float bf2f(unsigned short u) {
    return __builtin_bit_cast(float, (unsigned)u << 16);
}
__device__ __forceinline__ float softplus(float x) {
    return fmaxf(x, 0.f) + __logf(1.f + __expf(-fabsf(x)));
}
__device__ __forceinline__ unsigned cvt_pk_bf16(float lo, float hi) {
    unsigned r;
    asm("v_cvt_pk_bf16_f32 %0, %1, %2" : "=v"(r) : "v"(lo), "v"(hi));
    return r;
}
__device__ __forceinline__ void gl_lds16(const unsigned short* g, unsigned short* l) {
    __builtin_amdgcn_global_load_lds(
        (const __attribute__((address_space(1))) void*)g,
        (__attribute__((address_space(3))) void*)l, 16, 0, 0);
}

// ---------------- merged prep: blocks [0,512) K-convert, [512,1024) V-transpose, [1024,1056) cs ----
__global__ __launch_bounds__(256) void prep_all(
    const float* __restrict__ k, const float* __restrict__ v, const float* __restrict__ c,
    unsigned short* __restrict__ wsK, unsigned short* __restrict__ wsVt, float* __restrict__ wsCs)
{
    __shared__ unsigned short sT[64 * 132];
    const int blk = blockIdx.x, tid = threadIdx.x;
    if (blk < 512) {
        int t = blk * 256 + tid;
        for (int u = t; u < 524288; u += 131072) {
            float4 a = reinterpret_cast<const float4*>(k)[u * 2];
            float4 b = reinterpret_cast<const float4*>(k)[u * 2 + 1];
            short8 o;
            o[0]=(short)f2bf(a.x); o[1]=(short)f2bf(a.y); o[2]=(short)f2bf(a.z); o[3]=(short)f2bf(a.w);
            o[4]=(short)f2bf(b.x); o[5]=(short)f2bf(b.y); o[6]=(short)f2bf(b.z); o[7]=(short)f2bf(b.w);
            reinterpret_cast<short8*>(wsK)[u] = o;
        }
    } else if (blk < 1024) {
        const int vb = blk - 512;
        const int bh = vb >> 4, m0 = (vb & 15) * 64;
        const float* src = v + ((size_t)bh * 1024 + m0) * 128;
        for (int i = tid; i < 2048; i += 256) {
            int row = i >> 5, c4 = i & 31;
            float4 t = reinterpret_cast<const float4*>(src)[i];
            unsigned long long pk = (unsigned long long)f2bf(t.x)
                                  | ((unsigned long long)f2bf(t.y) << 16)
                                  | ((unsigned long long)f2bf(t.z) << 32)
                                  | ((unsigned long long)f2bf(t.w) << 48);
            *reinterpret_cast<unsigned long long*>(&sT[row * 132 + c4 * 4]) = pk;
        }
        __syncthreads();
        for (int u = tid; u < 2048; u += 256) {
            int dh = u >> 4, ms = u & 15;
            unsigned long long pk = (unsigned long long)sT[(ms*4+0)*132 + dh]
                                  | ((unsigned long long)sT[(ms*4+1)*132 + dh] << 16)
                                  | ((unsigned long long)sT[(ms*4+2)*132 + dh] << 32)
                                  | ((unsigned long long)sT[(ms*4+3)*132 + dh] << 48);
            *reinterpret_cast<unsigned long long*>(&wsVt[((size_t)bh * 128 + dh) * 1024 + m0 + ms * 4]) = pk;
        }
    } else {
        __shared__ float red[4];
        const int bh = blk - 1024;
        float p = 0.f;
        for (int i = tid; i < 1024; i += 256) p += softplus(c[(size_t)bh * 1024 + i]);
        p += __shfl_xor(p, 32, 64); p += __shfl_xor(p, 16, 64); p += __shfl_xor(p, 8, 64);
        p += __shfl_xor(p,  4, 64); p += __shfl_xor(p,  2, 64); p += __shfl_xor(p, 1, 64);
        if ((tid & 63) == 0) red[tid >> 6] = p;
        __syncthreads();
        if (tid == 0) wsCs[bh] = red[0] + red[1] + red[2] + red[3] + 1e-9f;
    }
}

// ---------------- main: 2-tile chunks, async dbuf staging ----------------
__global__ __launch_bounds__(512, 4) void sam_main(
    const float* __restrict__ q, const float* __restrict__ dqp, const float* __restrict__ dkp,
    const float* __restrict__ w_w, const float* __restrict__ b_w,
    const float* __restrict__ w_b, const float* __restrict__ b_b,
    const unsigned short* __restrict__ wsK, const unsigned short* __restrict__ wsVt,
    const float* __restrict__ wsCs, float* __restrict__ out)
{
    __shared__ __align__(16) unsigned short uSh[32768];  // 64KB: K/V chunk dbuf [2][128][128]; sQ; sO epilogue
    __shared__ __align__(16) unsigned short sPb[4096];   //  8KB: sP [32][128] swizzled; aliases s_red/s_inv
    float* s_red = reinterpret_cast<float*>(sPb);        // [128]
    float* s_inv = s_red + 128;                          // [32]

    const int bid  = blockIdx.x;
    const int xcd  = bid & 7;                 // round-robin XCD assumption (perf-only)
    const int j    = bid >> 3;                // 0..127 within XCD
    const int bh   = xcd * 4 + (j >> 5);      // bh-MAJOR: concurrent blocks share one bh (512KB, L2-hot)
    const int n0   = (j & 31) * 32;
    const int b    = bh >> 3;
    const int h    = bh & 7;
    const int tid  = threadIdx.x;
    const int lane = tid & 63;
    const int wave = tid >> 6;
    const int l15  = lane & 15;
    const int quad = lane >> 4;
    const int wr   = wave >> 2;               // row half (16 rows)
    const int wc   = wave & 3;                // col quarter (16 m) / dh quarter (32 dh)
    const int mq   = wc * 16 + l15;
    const int swz3 = l15 & 7;
    const int r0   = wr * 16 + quad * 4;
    const int q4   = (quad & 1) * 4;          // (r0+r)&7 = q4+r (no carry, r<4)

    const float ww = w_w[h], bw = b_w[h], wb = w_b[h], bb = b_b[h];
    const float wwn = -ww, bwn = -bw;
    const float SCALE = 0.08838834764831845f;   // 1/sqrt(128), folded into Q

    // ---- staging geometry (loop-invariant). chunk = 128 rows x 16 granules of 16B ----
    const unsigned short* gKbh = wsK  + (size_t)bh * 131072;
    const unsigned short* gVbh = wsVt + (size_t)bh * 131072;
    const int srow  = tid >> 4;                                 // staging row/dh (i=0): 0..31
    const int koff0 = srow * 128  + (((tid & 15) ^ (srow & 7)) << 3);
    const int voff0 = srow * 1024 + (((tid & 15) ^ (srow & 7)) << 3);
    const int ldsoW = wave * 512;                               // wave-uniform dest (shorts)

    auto stageK = [&](int buf, int c) {                         // K chunk c: rows [c*128, c*128+128)
        const unsigned short* g = gKbh + c * 16384 + koff0;
        #pragma unroll
        for (int i = 0; i < 4; i++)                             // rows +32 each: swizzle invariant
            gl_lds16(g + i * 4096, &uSh[buf * 16384 + ldsoW + i * 4096]);
    };
    auto stageV = [&](int buf, int c) {                         // V chunk c: m cols [c*128, ...)
        const unsigned short* g = gVbh + c * 128 + voff0;
        #pragma unroll
        for (int i = 0; i < 4; i++)                             // dh +32 each
            gl_lds16(g + i * 32768, &uSh[buf * 16384 + ldsoW + i * 4096]);
    };

    // ---- prologue: prefetch K chunk 0 into buf1; Q rows -> bf16 (pre-scaled) sQ (buf0) ----
    stageK(1, 0);
    {
        const float* qbase = q + ((size_t)bh * 1024 + n0) * 128;
        for (int i = tid; i < 1024; i += 512) {
            int row = i >> 5, c4 = i & 31;
            float4 t = reinterpret_cast<const float4*>(qbase)[i];
            unsigned long long pk = (unsigned long long)f2bf(t.x * SCALE)
                                  | ((unsigned long long)f2bf(t.y * SCALE) << 16)
                                  | ((unsigned long long)f2bf(t.z * SCALE) << 32)
                                  | ((unsigned long long)f2bf(t.w * SCALE) << 48);
            *reinterpret_cast<unsigned long long*>(&uSh[row * 136 + c4 * 4]) = pk;
        }
    }
    float qxm[4], qym[4], qzm[4], qs[4];
    #pragma unroll
    for (int r = 0; r < 4; r++) {
        float4 d4 = reinterpret_cast<const float4*>(dqp)[(size_t)b * 1024 + n0 + r0 + r];
        qxm[r] = -2.f * d4.x; qym[r] = -2.f * d4.y; qzm[r] = -2.f * d4.z;
        qs[r] = d4.x*d4.x + d4.y*d4.y + d4.z*d4.z;
    }
    const float cs = wsCs[bh];
    __syncthreads();                           // sQ visible; stageK(1,0) drained
    short8 afr[4];
    {
        const unsigned short* aq = &uSh[(wr * 16 + l15) * 136 + quad * 8];
        #pragma unroll
        for (int ks = 0; ks < 4; ks++)
            afr[ks] = *reinterpret_cast<const short8*>(aq + ks * 32);
    }
    __syncthreads();                           // all afr reads done; buf0 free

    const float4* dkb = reinterpret_cast<const float4*>(dkp) + (size_t)b * 1024 + mq;

    // ================= PASS 1: 8 chunks, 1 barrier/chunk =================
    float rs[4] = {0.f, 0.f, 0.f, 0.f};
    unsigned vreg[16][2];                      // raw-score cache: 16 tiles x 4 vals packed bf16
    #pragma unroll
    for (int c = 0; c < 8; c++) {
        const int rbuf = ((c & 1) ^ 1) * 16384;     // read buf: c0->1, c1->0, ...
        if (c < 7) stageK(c & 1, c + 1);            // async prefetch next chunk
        #pragma unroll
        for (int tt = 0; tt < 2; tt++) {
            const int t = c * 2 + tt;
            f32x4 cacc = {0.f, 0.f, 0.f, 0.f};
            const unsigned short* bq = &uSh[rbuf + (tt * 64 + mq) * 128];
            #pragma unroll
            for (int ks = 0; ks < 4; ks++) {
                short8 bfr = *reinterpret_cast<const short8*>(bq + (((ks * 4 + quad) ^ swz3) << 3));
                cacc = __builtin_amdgcn_mfma_f32_16x16x32_bf16(afr[ks], bfr, cacc, 0, 0, 0);
            }
            float4 d4 = dkb[t * 64];
            float ksq = d4.x*d4.x + d4.y*d4.y + d4.z*d4.z;
            float val[4];
            #pragma unroll
            for (int r = 0; r < 4; r++) {
                float dist = qs[r] + ksq + qxm[r]*d4.x + qym[r]*d4.y + qzm[r]*d4.z;
                float aw = softplus(dist * wwn + bwn);
                float ab = dist * wb + bb;
                val[r] = fmaxf(cacc[r] * aw + ab, 0.f);
                rs[r] += val[r];
            }
            vreg[t][0] = cvt_pk_bf16(val[0], val[1]);
            vreg[t][1] = cvt_pk_bf16(val[2], val[3]);
        }
        __syncthreads();                       // cur-buf reads done + next stage landed
    }

    // ---- transition: rowsums -> invd; prefetch V chunk 0 into buf0 ----
    stageV(0, 0);
    #pragma unroll
    for (int r = 0; r < 4; r++) {
        float ts = rs[r];
        ts += __shfl_xor(ts, 1, 64);
        ts += __shfl_xor(ts, 2, 64);
        ts += __shfl_xor(ts, 4, 64);
        ts += __shfl_xor(ts, 8, 64);
        if (l15 == 0) s_red[wc * 32 + r0 + r] = ts;
    }
    __syncthreads();                           // s_red visible (stageV(0) drains here too)
    if (tid < 32) s_inv[tid] = 1.f / (s_red[tid] + s_red[32 + tid] + s_red[64 + tid] + s_red[96 + tid] + cs);
    __syncthreads();
    float inv4[4];
    #pragma unroll
    for (int r = 0; r < 4; r++) inv4[r] = s_inv[r0 + r];
    const int crow = tid >> 4, cc4 = tid & 15;             // cooperative-store coords
    const float cinv = s_inv[crow];
    __syncthreads();                           // all s_inv reads done; sPb region free

    // ================= REPLAY: 8 chunks x (sp_write | A | stageV+stores+PV | B) =================
    f32x4 oacc[2];
    oacc[0] = {0.f, 0.f, 0.f, 0.f};
    oacc[1] = {0.f, 0.f, 0.f, 0.f};
    float* scrow = out + OUT_ELEMS + ((size_t)bh << 20) + (size_t)(n0 + crow) * 1024 + cc4 * 8;
    const int prow = wr * 16 + l15;
    const int gm = mq >> 3, c7 = mq & 7;

    #pragma unroll
    for (int c = 0; c < 8; c++) {
        const int vbuf = (c & 1) * 16384;      // V chunk c lives in buf (c&1)
        {   // sP write: sub-tile0 (cols mq) + sub-tile1 (cols 64+mq), granule-XOR swizzled
            unsigned a0 = vreg[c*2][0],   a1 = vreg[c*2][1];
            unsigned b0 = vreg[c*2+1][0], b1 = vreg[c*2+1][1];
            sPb[(r0+0)*128 + ((( gm      ^ (q4+0)) << 3) | c7)] = (unsigned short)a0;
            sPb[(r0+1)*128 + ((( gm      ^ (q4+1)) << 3) | c7)] = (unsigned short)(a0 >> 16);
            sPb[(r0+2)*128 + ((( gm      ^ (q4+2)) << 3) | c7)] = (unsigned short)a1;
            sPb[(r0+3)*128 + ((( gm      ^ (q4+3)) << 3) | c7)] = (unsigned short)(a1 >> 16);
            sPb[(r0+0)*128 + ((((8|gm)   ^ (q4+0)) << 3) | c7)] = (unsigned short)b0;
            sPb[(r0+1)*128 + ((((8|gm)   ^ (q4+1)) << 3) | c7)] = (unsigned short)(b0 >> 16);
            sPb[(r0+2)*128 + ((((8|gm)   ^ (q4+2)) << 3) | c7)] = (unsigned short)b1;
            sPb[(r0+3)*128 + ((((8|gm)   ^ (q4+3)) << 3) | c7)] = (unsigned short)(b1 >> 16);
        }
        __syncthreads();                       // A: sP visible
        if (c < 7) stageV((c & 1) ^ 1, c + 1); // async: drains at B under stores+PV
        {   // cooperative coalesced score store: 512B per row, nontemporal
            short8 pk8 = *reinterpret_cast<const short8*>(&sPb[crow * 128 + ((cc4 ^ (crow & 7)) << 3)]);
            f32x4 o1, o2;
            o1[0] = bf2f((unsigned short)pk8[0]) * cinv;
            o1[1] = bf2f((unsigned short)pk8[1]) * cinv;
            o1[2] = bf2f((unsigned short)pk8[2]) * cinv;
            o1[3] = bf2f((unsigned short)pk8[3]) * cinv;
            o2[0] = bf2f((unsigned short)pk8[4]) * cinv;
            o2[1] = bf2f((unsigned short)pk8[5]) * cinv;
            o2[2] = bf2f((unsigned short)pk8[6]) * cinv;
            o2[3] = bf2f((unsigned short)pk8[7]) * cinv;
            __builtin_nontemporal_store(o1, reinterpret_cast<f32x4*>(scrow + c * 128));
            __builtin_nontemporal_store(o2, reinterpret_cast<f32x4*>(scrow + c * 128 + 4));
        }
        #pragma unroll
        for (int tt = 0; tt < 2; tt++) {
            #pragma unroll
            for (int ks2 = 0; ks2 < 2; ks2++) {
                const int gP = tt * 8 + ks2 * 4 + quad;
                short8 pfr = *reinterpret_cast<const short8*>(
                    &sPb[prow * 128 + ((gP ^ (prow & 7)) << 3)]);
                #pragma unroll
                for (int df = 0; df < 2; df++) {
                    const int dh = wc * 32 + df * 16 + l15;
                    short8 vfr = *reinterpret_cast<const short8*>(
                        &uSh[vbuf + dh * 128 + ((gP ^ swz3) << 3)]);
                    oacc[df] = __builtin_amdgcn_mfma_f32_16x16x32_bf16(pfr, vfr, oacc[df], 0, 0, 0);
                }
            }
        }
        __syncthreads();                       // B: sP/V reads done; stage + NT stores drained
    }

    // ---- epilogue: O -> LDS fp32 [32][136] -> cooperative full-line NT stores ----
    {
        float* sO = reinterpret_cast<float*>(uSh);
        #pragma unroll
        for (int df = 0; df < 2; df++)
            #pragma unroll
            for (int r = 0; r < 4; r++)
                sO[(r0 + r) * 136 + wc * 32 + df * 16 + l15] = oacc[df][r] * inv4[r];
        __syncthreads();
        const float* src = &sO[crow * 136 + cc4 * 8];
        f32x4 a = *reinterpret_cast<const f32x4*>(src);
        f32x4 d = *reinterpret_cast<const f32x4*>(src + 4);
        float* obase = out + ((size_t)bh * 1024 + n0 + crow) * 128 + cc4 * 8;
        __builtin_nontemporal_store(a, reinterpret_cast<f32x4*>(obase));
        __builtin_nontemporal_store(d, reinterpret_cast<f32x4*>(obase + 4));
    }
}

extern "C" void kernel_launch(void* const* d_in, const int* in_sizes, int n_in,
                              void* d_out, int out_size, void* d_ws, size_t ws_size,
                              hipStream_t stream) {
    const float* q   = (const float*)d_in[0];
    const float* k   = (const float*)d_in[1];
    const float* v   = (const float*)d_in[2];
    const float* c   = (const float*)d_in[3];
    const float* dq  = (const float*)d_in[4];
    const float* dk  = (const float*)d_in[5];
    const float* w_w = (const float*)d_in[6];
    const float* b_w = (const float*)d_in[7];
    const float* w_b = (const float*)d_in[8];
    const float* b_b = (const float*)d_in[9];
    float* out = (float*)d_out;
    char* ws = (char*)d_ws;
    unsigned short* wsK  = (unsigned short*)(ws + WS_K);
    unsigned short* wsVt = (unsigned short*)(ws + WS_VT);
    float* wsCs   = (float*)(ws + WS_CS);

    hipLaunchKernelGGL(prep_all, dim3(1056), dim3(256), 0, stream, k, v, c, wsK, wsVt, wsCs);
    hipLaunchKernelGGL(sam_main, dim3(1024), dim3(512), 0, stream,
                       q, dq, dk, w_w, b_w, w_b, b_b, wsK, wsVt, wsCs, out);
}

// Round 7
// 258.945 us; speedup vs baseline: 1.0183x; 1.0183x over previous
//
#include <hip/hip_runtime.h>

// RelativeSAMAttention: B=4,H=8,N=1024,DH=128. Outputs FP32: out[B,H,N,DH] ++ scores[B,H,N,N].
//
// R10: recomposition of VERIFIED pieces only (R9 lesson: replay restructure caused the
// regression; pass1-chunking + sO epilogue were fine but bundled with it):
//   - pass1: R9's 2-tile (128-col) chunk staging, 8 barriers (verbatim).
//   - replay: R8's 64-col tiles, sP DOUBLE-buffered, 1 barrier/tile (verbatim; measured 88.4us).
//   - epilogue: R9's sO-via-LDS full-line NT stores (kills out's 64B-segment RMW: -17..23MB W).
//   - launch_bounds(512,4): R6/R7b lesson — tighter caps spill the 32-VGPR score cache.
//   - LDS 74.4KB -> 2 blocks/CU.

typedef __attribute__((ext_vector_type(8))) short short8;
typedef __attribute__((ext_vector_type(4))) float f32x4;

#define OUT_ELEMS 4194304ull
#define WS_K      0ull           //  8388608 B bf16 K [bh][m][dh]
#define WS_VT     8388608ull     //  8388608 B bf16 V^T [bh][dh][m]
#define WS_CS     16777216ull    //      128 B fp32 cs[32]

__device__ __forceinline__ unsigned short f2bf(float f) {
    unsigned u = __builtin_bit_cast(unsigned, f);
    u += 0x7FFFu + ((u >> 16) & 1u);
    return (unsigned short)(u >> 16);
}
__device__ __forceinline__ float bf2f(unsigned short u) {
    return __builtin_bit_cast(float, (unsigned)u << 16);
}
__device__ __forceinline__ float softplus(float x) {
    return fmaxf(x, 0.f) + __logf(1.f + __expf(-fabsf(x)));
}
__device__ __forceinline__ unsigned cvt_pk_bf16(float lo, float hi) {
    unsigned r;
    asm("v_cvt_pk_bf16_f32 %0, %1, %2" : "=v"(r) : "v"(lo), "v"(hi));
    return r;
}
__device__ __forceinline__ void gl_lds16(const unsigned short* g, unsigned short* l) {
    __builtin_amdgcn_global_load_lds(
        (const __attribute__((address_space(1))) void*)g,
        (__attribute__((address_space(3))) void*)l, 16, 0, 0);
}

// ---------------- merged prep: blocks [0,512) K-convert, [512,1024) V-transpose, [1024,1056) cs ----
__global__ __launch_bounds__(256) void prep_all(
    const float* __restrict__ k, const float* __restrict__ v, const float* __restrict__ c,
    unsigned short* __restrict__ wsK, unsigned short* __restrict__ wsVt, float* __restrict__ wsCs)
{
    __shared__ unsigned short sT[64 * 132];
    const int blk = blockIdx.x, tid = threadIdx.x;
    if (blk < 512) {
        int t = blk * 256 + tid;
        for (int u = t; u < 524288; u += 131072) {
            float4 a = reinterpret_cast<const float4*>(k)[u * 2];
            float4 b = reinterpret_cast<const float4*>(k)[u * 2 + 1];
            short8 o;
            o[0]=(short)f2bf(a.x); o[1]=(short)f2bf(a.y); o[2]=(short)f2bf(a.z); o[3]=(short)f2bf(a.w);
            o[4]=(short)f2bf(b.x); o[5]=(short)f2bf(b.y); o[6]=(short)f2bf(b.z); o[7]=(short)f2bf(b.w);
            reinterpret_cast<short8*>(wsK)[u] = o;
        }
    } else if (blk < 1024) {
        const int vb = blk - 512;
        const int bh = vb >> 4, m0 = (vb & 15) * 64;
        const float* src = v + ((size_t)bh * 1024 + m0) * 128;
        for (int i = tid; i < 2048; i += 256) {
            int row = i >> 5, c4 = i & 31;
            float4 t = reinterpret_cast<const float4*>(src)[i];
            unsigned long long pk = (unsigned long long)f2bf(t.x)
                                  | ((unsigned long long)f2bf(t.y) << 16)
                                  | ((unsigned long long)f2bf(t.z) << 32)
                                  | ((unsigned long long)f2bf(t.w) << 48);
            *reinterpret_cast<unsigned long long*>(&sT[row * 132 + c4 * 4]) = pk;
        }
        __syncthreads();
        for (int u = tid; u < 2048; u += 256) {
            int dh = u >> 4, ms = u & 15;
            unsigned long long pk = (unsigned long long)sT[(ms*4+0)*132 + dh]
                                  | ((unsigned long long)sT[(ms*4+1)*132 + dh] << 16)
                                  | ((unsigned long long)sT[(ms*4+2)*132 + dh] << 32)
                                  | ((unsigned long long)sT[(ms*4+3)*132 + dh] << 48);
            *reinterpret_cast<unsigned long long*>(&wsVt[((size_t)bh * 128 + dh) * 1024 + m0 + ms * 4]) = pk;
        }
    } else {
        __shared__ float red[4];
        const int bh = blk - 1024;
        float p = 0.f;
        for (int i = tid; i < 1024; i += 256) p += softplus(c[(size_t)bh * 1024 + i]);
        p += __shfl_xor(p, 32, 64); p += __shfl_xor(p, 16, 64); p += __shfl_xor(p, 8, 64);
        p += __shfl_xor(p,  4, 64); p += __shfl_xor(p,  2, 64); p += __shfl_xor(p, 1, 64);
        if ((tid & 63) == 0) red[tid >> 6] = p;
        __syncthreads();
        if (tid == 0) wsCs[bh] = red[0] + red[1] + red[2] + red[3] + 1e-9f;
    }
}

// ---------------- main: chunked pass1 (8 barriers) + R8 replay (1 barrier/tile) ----------------
__global__ __launch_bounds__(512, 4) void sam_main(
    const float* __restrict__ q, const float* __restrict__ dqp, const float* __restrict__ dkp,
    const float* __restrict__ w_w, const float* __restrict__ b_w,
    const float* __restrict__ w_b, const float* __restrict__ b_b,
    const unsigned short* __restrict__ wsK, const unsigned short* __restrict__ wsVt,
    const float* __restrict__ wsCs, float* __restrict__ out)
{
    __shared__ __align__(16) unsigned short uSh[32768];  // 64KB: pass1 K-chunk dbuf [2][128][128]; replay V dbuf [2][64][128]@[0,16384); sQ; sO
    __shared__ __align__(16) unsigned short sPb[4096];   //  8KB: sP[2][32][64], granule-XOR swizzled
    __shared__ float s_red[128];
    __shared__ float s_inv[32];

    const int bid  = blockIdx.x;
    const int xcd  = bid & 7;                 // round-robin XCD assumption (perf-only)
    const int j    = bid >> 3;                // 0..127 within XCD
    const int bh   = xcd * 4 + (j >> 5);      // bh-MAJOR: concurrent blocks share one bh (512KB, L2-hot)
    const int n0   = (j & 31) * 32;
    const int b    = bh >> 3;
    const int h    = bh & 7;
    const int tid  = threadIdx.x;
    const int lane = tid & 63;
    const int wave = tid >> 6;
    const int l15  = lane & 15;
    const int quad = lane >> 4;
    const int wr   = wave >> 2;               // row half (16 rows)
    const int wc   = wave & 3;                // col quarter (16 m) / dh quarter (32 dh)
    const int mq   = wc * 16 + l15;
    const int swz3 = l15 & 7;
    const int r0   = wr * 16 + quad * 4;
    const int q4   = (quad & 1) * 4;          // (r0+r)&7 = q4+r (no carry, r<4)

    const float ww = w_w[h], bw = b_w[h], wb = w_b[h], bb = b_b[h];
    const float wwn = -ww, bwn = -bw;
    const float SCALE = 0.08838834764831845f;   // 1/sqrt(128), folded into Q

    // ---- staging geometry ----
    const unsigned short* gKbh = wsK  + (size_t)bh * 131072;
    const unsigned short* gVbh = wsVt + (size_t)bh * 131072;
    const int srow   = tid >> 4;                                // K-chunk staging row (i=0): 0..31
    const int koff0  = srow * 128 + (((tid & 15) ^ (srow & 7)) << 3);
    const int vdh    = tid >> 3;                                // V-tile staging dh (i=0): 0..63
    const int voff0  = vdh * 1024 + (((tid & 7) ^ (vdh & 7)) << 3);
    const int ldsoW  = wave * 512;                              // wave-uniform dest (shorts)

    auto stageK = [&](int buf, int c) {                         // pass1: K chunk c = rows [c*128, c*128+128)
        const unsigned short* g = gKbh + c * 16384 + koff0;
        #pragma unroll
        for (int i = 0; i < 4; i++)                             // rows +32 each: swizzle invariant
            gl_lds16(g + i * 4096, &uSh[buf * 16384 + ldsoW + i * 4096]);
    };
    auto stageV = [&](int buf, int t) {                         // replay: V tile t = m cols [t*64, t*64+64)
        const unsigned short* g = gVbh + t * 64 + voff0;
        gl_lds16(g,         &uSh[buf * 8192 + ldsoW]);
        gl_lds16(g + 65536, &uSh[buf * 8192 + 4096 + ldsoW]);   // dh+64: same low3 bits
    };

    // ---- prologue: prefetch K chunk 0 into buf1; Q rows -> bf16 (pre-scaled) sQ (buf0) ----
    stageK(1, 0);
    {
        const float* qbase = q + ((size_t)bh * 1024 + n0) * 128;
        for (int i = tid; i < 1024; i += 512) {
            int row = i >> 5, c4 = i & 31;
            float4 t = reinterpret_cast<const float4*>(qbase)[i];
            unsigned long long pk = (unsigned long long)f2bf(t.x * SCALE)
                                  | ((unsigned long long)f2bf(t.y * SCALE) << 16)
                                  | ((unsigned long long)f2bf(t.z * SCALE) << 32)
                                  | ((unsigned long long)f2bf(t.w * SCALE) << 48);
            *reinterpret_cast<unsigned long long*>(&uSh[row * 136 + c4 * 4]) = pk;
        }
    }
    float qxm[4], qym[4], qzm[4], qs[4];
    #pragma unroll
    for (int r = 0; r < 4; r++) {
        float4 d4 = reinterpret_cast<const float4*>(dqp)[(size_t)b * 1024 + n0 + r0 + r];
        qxm[r] = -2.f * d4.x; qym[r] = -2.f * d4.y; qzm[r] = -2.f * d4.z;
        qs[r] = d4.x*d4.x + d4.y*d4.y + d4.z*d4.z;
    }
    const float cs = wsCs[bh];
    __syncthreads();                           // sQ visible; stageK(1,0) drained
    short8 afr[4];
    {
        const unsigned short* aq = &uSh[(wr * 16 + l15) * 136 + quad * 8];
        #pragma unroll
        for (int ks = 0; ks < 4; ks++)
            afr[ks] = *reinterpret_cast<const short8*>(aq + ks * 32);
    }
    __syncthreads();                           // all afr reads done; buf0 free

    const float4* dkb = reinterpret_cast<const float4*>(dkp) + (size_t)b * 1024 + mq;

    // ================= PASS 1: 8 chunks, 1 barrier/chunk (R9 verbatim) =================
    float rs[4] = {0.f, 0.f, 0.f, 0.f};
    unsigned vreg[16][2];                      // raw-score cache: 16 tiles x 4 vals packed bf16
    #pragma unroll
    for (int c = 0; c < 8; c++) {
        const int rbuf = ((c & 1) ^ 1) * 16384;     // read buf: c0->1, c1->0, ...
        if (c < 7) stageK(c & 1, c + 1);            // async prefetch next chunk
        #pragma unroll
        for (int tt = 0; tt < 2; tt++) {
            const int t = c * 2 + tt;
            f32x4 cacc = {0.f, 0.f, 0.f, 0.f};
            const unsigned short* bq = &uSh[rbuf + (tt * 64 + mq) * 128];
            #pragma unroll
            for (int ks = 0; ks < 4; ks++) {
                short8 bfr = *reinterpret_cast<const short8*>(bq + (((ks * 4 + quad) ^ swz3) << 3));
                cacc = __builtin_amdgcn_mfma_f32_16x16x32_bf16(afr[ks], bfr, cacc, 0, 0, 0);
            }
            float4 d4 = dkb[t * 64];
            float ksq = d4.x*d4.x + d4.y*d4.y + d4.z*d4.z;
            float val[4];
            #pragma unroll
            for (int r = 0; r < 4; r++) {
                float dist = qs[r] + ksq + qxm[r]*d4.x + qym[r]*d4.y + qzm[r]*d4.z;
                float aw = softplus(dist * wwn + bwn);
                float ab = dist * wb + bb;
                val[r] = fmaxf(cacc[r] * aw + ab, 0.f);
                rs[r] += val[r];
            }
            vreg[t][0] = cvt_pk_bf16(val[0], val[1]);
            vreg[t][1] = cvt_pk_bf16(val[2], val[3]);
        }
        __syncthreads();                       // cur-buf reads done + next stage landed
    }

    // ---- transition (R8 verbatim, stageV now safe after final pass1 barrier) ----
    #pragma unroll
    for (int r = 0; r < 4; r++) {
        float ts = rs[r];
        ts += __shfl_xor(ts, 1, 64);
        ts += __shfl_xor(ts, 2, 64);
        ts += __shfl_xor(ts, 4, 64);
        ts += __shfl_xor(ts, 8, 64);
        if (l15 == 0) s_red[wc * 32 + r0 + r] = ts;
    }
    auto sp_write = [&](int buf, unsigned pv0, unsigned pv1) {
        unsigned short* pb = sPb + buf * 2048;
        const int gm = mq >> 3, c7 = mq & 7;
        pb[(r0 + 0) * 64 + (((gm ^ (q4 + 0)) << 3) | c7)] = (unsigned short)(pv0);
        pb[(r0 + 1) * 64 + (((gm ^ (q4 + 1)) << 3) | c7)] = (unsigned short)(pv0 >> 16);
        pb[(r0 + 2) * 64 + (((gm ^ (q4 + 2)) << 3) | c7)] = (unsigned short)(pv1);
        pb[(r0 + 3) * 64 + (((gm ^ (q4 + 3)) << 3) | c7)] = (unsigned short)(pv1 >> 16);
    };
    stageV(0, 0);                              // buf0 free after pass1's final barrier
    sp_write(0, vreg[0][0], vreg[0][1]);
    __syncthreads();
    if (tid < 32) s_inv[tid] = 1.f / (s_red[tid] + s_red[32 + tid] + s_red[64 + tid] + s_red[96 + tid] + cs);
    __syncthreads();

    float inv4[4];
    #pragma unroll
    for (int r = 0; r < 4; r++) inv4[r] = s_inv[r0 + r];

    // ================= REPLAY (R8 verbatim): 1 barrier/tile; coop NT score store + PV =================
    f32x4 oacc[2];
    oacc[0] = {0.f, 0.f, 0.f, 0.f};
    oacc[1] = {0.f, 0.f, 0.f, 0.f};
    const int crow = tid >> 4, cc4 = tid & 15;             // cooperative-store coords
    const int cidx = crow * 64 + ((((cc4 >> 1) ^ (crow & 7)) << 3) | ((cc4 & 1) << 2));
    float* scrow = out + OUT_ELEMS + ((size_t)bh << 20) + (size_t)(n0 + crow) * 1024 + cc4 * 4;
    const float cinv = s_inv[crow];
    const int prow = wr * 16 + l15;

    #pragma unroll
    for (int t = 0; t < 16; t++) {
        const int bb2 = t & 1;
        if (t < 15) {
            stageV(bb2 ^ 1, t + 1);
            sp_write(bb2 ^ 1, vreg[t + 1][0], vreg[t + 1][1]);
        }
        {   // cooperative coalesced score store: full 128B lines, nontemporal
            unsigned long long pk = *reinterpret_cast<const unsigned long long*>(&sPb[bb2 * 2048 + cidx]);
            f32x4 o;
            o[0] = bf2f((unsigned short)(pk      )) * cinv;
            o[1] = bf2f((unsigned short)(pk >> 16)) * cinv;
            o[2] = bf2f((unsigned short)(pk >> 32)) * cinv;
            o[3] = bf2f((unsigned short)(pk >> 48)) * cinv;
            __builtin_nontemporal_store(o, reinterpret_cast<f32x4*>(scrow + t * 64));
        }
        #pragma unroll
        for (int ks2 = 0; ks2 < 2; ks2++) {
            short8 pfr = *reinterpret_cast<const short8*>(
                &sPb[bb2 * 2048 + prow * 64 + (((ks2 * 4 + quad) ^ swz3) << 3)]);
            #pragma unroll
            for (int df = 0; df < 2; df++) {
                const int dh = wc * 32 + df * 16 + l15;
                short8 vfr = *reinterpret_cast<const short8*>(
                    &uSh[bb2 * 8192 + dh * 64 + (((ks2 * 4 + quad) ^ swz3) << 3)]);
                oacc[df] = __builtin_amdgcn_mfma_f32_16x16x32_bf16(pfr, vfr, oacc[df], 0, 0, 0);
            }
        }
        if (t < 15) __syncthreads();           // cur reads done before next overwrites
    }

    // ---- epilogue: O -> LDS fp32 [32][136] -> cooperative full-line NT stores ----
    {
        __syncthreads();                       // t=15 reads (sPb/uSh buf1) done before aliasing uSh
        float* sO = reinterpret_cast<float*>(uSh);
        #pragma unroll
        for (int df = 0; df < 2; df++)
            #pragma unroll
            for (int r = 0; r < 4; r++)
                sO[(r0 + r) * 136 + wc * 32 + df * 16 + l15] = oacc[df][r] * inv4[r];
        __syncthreads();
        const float* src = &sO[crow * 136 + cc4 * 8];
        f32x4 a = *reinterpret_cast<const f32x4*>(src);
        f32x4 d = *reinterpret_cast<const f32x4*>(src + 4);
        float* obase = out + ((size_t)bh * 1024 + n0 + crow) * 128 + cc4 * 8;
        __builtin_nontemporal_store(a, reinterpret_cast<f32x4*>(obase));
        __builtin_nontemporal_store(d, reinterpret_cast<f32x4*>(obase + 4));
    }
}

extern "C" void kernel_launch(void* const* d_in, const int* in_sizes, int n_in,
                              void* d_out, int out_size, void* d_ws, size_t ws_size,
                              hipStream_t stream) {
    const float* q   = (const float*)d_in[0];
    const float* k   = (const float*)d_in[1];
    const float* v   = (const float*)d_in[2];
    const float* c   = (const float*)d_in[3];
    const float* dq  = (const float*)d_in[4];
    const float* dk  = (const float*)d_in[5];
    const float* w_w = (const float*)d_in[6];
    const float* b_w = (const float*)d_in[7];
    const float* w_b = (const float*)d_in[8];
    const float* b_b = (const float*)d_in[9];
    float* out = (float*)d_out;
    char* ws = (char*)d_ws;
    unsigned short* wsK  = (unsigned short*)(ws + WS_K);
    unsigned short* wsVt = (unsigned short*)(ws + WS_VT);
    float* wsCs   = (float*)(ws + WS_CS);

    hipLaunchKernelGGL(prep_all, dim3(1056), dim3(256), 0, stream, k, v, c, wsK, wsVt, wsCs);
    hipLaunchKernelGGL(sam_main, dim3(1024), dim3(512), 0, stream,
                       q, dq, dk, w_w, b_w, w_b, b_b, wsK, wsVt, wsCs, out);
}